// Round 11
// baseline (67.672 us; speedup 1.0000x reference)
//
#include <hip/hip_runtime.h>
#include <math.h>

constexpr int Bn = 64, Sn = 6, Tn = 2000, Cn = 25;
constexpr int COLS = Sn * Tn;              // 12000
constexpr int ROWS = Bn * Sn * Tn;         // 768000
constexpr int BDIM = 256;
constexpr int WV   = 4;                    // waves per block

// ---- fret: 64-row tiles, wave-autonomous double-buffered pipeline (R7 engine) ----
constexpr int TROWS = 64;                  // rows per tile (1 per lane)
constexpr int TF4   = TROWS * Cn / 4;      // 400 float4 per tile (6.4 KB)
constexpr int NTIL  = ROWS / TROWS;        // 12000 tiles
constexpr int NC    = 8;                   // queue shards (address parallelism)
constexpr int TPC   = NTIL / NC;           // 1500 tiles per shard
constexpr int Q     = 2;                   // tiles per grab (42M atomics/s/shard)

// ---- onset: 64 cols per block, wave w covers batch [16w,16w+16) (R7 verbatim) ----
constexpr int OCOLS = 64;
constexpr int OBLK  = (COLS + OCOLS - 1) / OCOLS;   // 188 onset blocks
constexpr int NFB   = 768;                 // fret worker blocks (3 per CU)
constexpr int GRID  = OBLK + NFB;          // 956
constexpr int PAD   = 1024;                // partial-array leading dim

typedef const __attribute__((address_space(1))) unsigned int guint;
typedef __attribute__((address_space(3)))       unsigned int luint;

__device__ int qctr[NC];                   // zero at module load; finish resets each run

// Segmented (<=2 contiguous strings per wave) butterfly reduce + LDS add.
static __device__ __forceinline__ void seg_reduce_add(float* ls, int s, float v, int lane) {
    const int s0 = __shfl(s, 0, 64);
    const int s1 = __shfl(s, 63, 64);
    if (s0 == s1) {                         // wave-uniform branch
        float a = v;
        #pragma unroll
        for (int off = 32; off; off >>= 1) a += __shfl_xor(a, off, 64);
        if (lane == 0) atomicAdd(&ls[s0], a);
    } else {
        float a = (s == s0) ? v : 0.0f;
        float b = (s == s0) ? 0.0f : v;
        #pragma unroll
        for (int off = 32; off; off >>= 1) {
            a += __shfl_xor(a, off, 64);
            b += __shfl_xor(b, off, 64);
        }
        if (lane == 0) { atomicAdd(&ls[s0], a); atomicAdd(&ls[s1], b); }
    }
}

__global__ __launch_bounds__(BDIM) void main_kernel(const float4* __restrict__ x4,
                                                    const int*    __restrict__ tgt,
                                                    const float*  __restrict__ ox,
                                                    const float*  __restrict__ ot,
                                                    float* __restrict__ pf,
                                                    float* __restrict__ po) {
    __shared__ float4 buf4[WV][2][TF4];    // 51.2 KB wave-private double buffers
    __shared__ int    tbuf[WV][2][TROWS];  // 2 KB async-staged targets
    __shared__ float  ws[WV][Sn];
    const int tid  = threadIdx.x;
    const int lane = tid & 63;
    const int w    = tid >> 6;
    const int b    = blockIdx.x;
    if (lane < Sn) ws[w][lane] = 0.0f;     // same-wave DS order: no barrier

    if (b < OBLK) {
        // ============ onset path: softmax over B, batch-split across waves ============
        const int cb  = b;
        const int col = cb * OCOLS + lane;            // wave-local column
        float4* ob4 = &buf4[0][0][0];                 // reuse fret buffer: [4][64] float4
        float M = -INFINITY, S = 0.0f, ts = 0.0f, txs = 0.0f;
        if (col < COLS) {
            const int b0 = w * 16;
            #pragma unroll
            for (int h = 0; h < 2; ++h) {             // two 8-batch chunks (reg pressure)
                float xv[8], tv[8];
                #pragma unroll
                for (int k = 0; k < 8; ++k) xv[k] = ox[(b0 + h * 8 + k) * COLS + col];
                #pragma unroll
                for (int k = 0; k < 8; ++k) tv[k] = ot[(b0 + h * 8 + k) * COLS + col];
                float cm = -INFINITY;
                #pragma unroll
                for (int k = 0; k < 8; ++k) cm = fmaxf(cm, xv[k]);
                float cs = 0.0f;
                #pragma unroll
                for (int k = 0; k < 8; ++k) cs += __expf(xv[k] - cm);
                const float nm = fmaxf(M, cm);
                S = S * __expf(M - nm) + cs * __expf(cm - nm);   // exp(-inf)=0 first iter
                M = nm;
                #pragma unroll
                for (int k = 0; k < 8; ++k) { ts += tv[k]; txs += tv[k] * xv[k]; }
            }
        }
        ob4[w * OCOLS + lane] = make_float4(M, S, ts, txs);   // per-wave partial
        __syncthreads();
        if (tid < OCOLS) {                            // wave 0 merges the 4 partials
            float on = 0.0f;
            int   s  = Sn - 1;
            const int c = cb * OCOLS + tid;
            if (c < COLS) {
                s = c / Tn;
                float4 p0 = ob4[0 * OCOLS + tid];
                float Mm = p0.x, Sm = p0.y, tsm = p0.z, txm = p0.w;
                #pragma unroll
                for (int q = 1; q < WV; ++q) {
                    const float4 p = ob4[q * OCOLS + tid];
                    const float nm = fmaxf(Mm, p.x);
                    Sm  = Sm * __expf(Mm - nm) + p.y * __expf(p.x - nm);
                    Mm  = nm;
                    tsm += p.z; txm += p.w;
                }
                on = tsm * (Mm + __logf(Sm)) - txm;
            }
            seg_reduce_add(ws[0], s, on, tid);        // wave 0 only, same-wave DS order
            if (tid < Sn) po[tid * PAD + cb] = ws[0][tid];
        }
    } else {
        // ===== fret path: R7 pipeline, tiles pulled from a sharded dynamic queue =====
        const int fb = b - OBLK;
        const int c  = (fb * WV + w) & (NC - 1);      // shard: ~384 waves each, uniform
        float4* bb = &buf4[w][0][0];                  // [2][TF4] wave-private

        int base = 0, lim = 0;
        auto next_tile = [&]() -> int {               // local tile in [0,TPC), or -1
            if (base >= lim) {                        // grab next chunk (1 atomic/wave)
                int idx = 0;
                if (lane == 0) idx = atomicAdd(&qctr[c], 1);
                idx  = __shfl(idx, 0, 64);
                base = idx * Q;
                lim  = base + Q;                      // TPC % Q == 0: no partial chunk
            }
            if (base >= TPC) return -1;               // sticky exhaust: no re-grab
            return base++;
        };

        // stage(lt,p): 7 x global_load_lds (tile) + 1 x 4B (targets) = 8 vmcnt ops.
        auto stage = [&](int lt, int p) {
            const int gt = c * TPC + lt;
            const float4* gs = x4 + (long)gt * TF4 + lane;
            #pragma unroll
            for (int k = 0; k < 6; ++k)
                __builtin_amdgcn_global_load_lds((guint*)(gs + k * 64),
                                                 (luint*)(bb + p * TF4 + k * 64), 16, 0, 0);
            if (lane < 16)
                __builtin_amdgcn_global_load_lds((guint*)(gs + 384),
                                                 (luint*)(bb + p * TF4 + 384), 16, 0, 0);
            __builtin_amdgcn_global_load_lds((guint*)(tgt + (long)gt * TROWS + lane),
                                             (luint*)&tbuf[w][p][0], 4, 0, 0);
        };

        auto compute = [&](int lt, int p) {
            const int gt = c * TPC + lt;
            const int tc = tbuf[w][p][lane];
            const float* rp = (const float*)(bb + p * TF4) + lane * Cn;  // stride 25
            float m = -INFINITY, xt = 0.0f;
            #pragma unroll
            for (int cc = 0; cc < Cn; ++cc) {
                const float e = rp[cc];
                m  = fmaxf(m, e);
                xt = (cc == tc) ? e : xt;             // select: no runtime reg index
            }
            float ss = 0.0f;
            #pragma unroll
            for (int cc = 0; cc < Cn; ++cc) ss += __expf(rp[cc] - m);
            const float nll = m + __logf(ss) - xt;
            const int s = ((gt * TROWS + lane) / Tn) % Sn;   // tile: <=2 strings
            seg_reduce_add(ws[w], s, nll, lane);
        };

        // Rolling double-buffered pipeline: never drains until the queue is empty.
        int t0 = next_tile();
        if (t0 >= 0) stage(t0, 0);
        int t1 = next_tile();
        if (t1 >= 0) stage(t1, 1);
        int p = 0;
        while (t0 >= 0) {
            if (t1 >= 0) asm volatile("s_waitcnt vmcnt(8)" ::: "memory");  // t0 done; t1 flying
            else         asm volatile("s_waitcnt vmcnt(0)" ::: "memory");  // final drain
            compute(t0, p);
            int t2 = -1;
            if (t1 >= 0) t2 = next_tile();            // grab overlaps next compute
            if (t2 >= 0) {
                asm volatile("s_waitcnt lgkmcnt(0)" ::: "memory");  // buf[p] reads retired
                stage(t2, p);                                       // overwrite buffer p
            }
            t0 = t1; t1 = t2; p ^= 1;
        }
        __syncthreads();                              // once per block: combine 4 waves
        if (tid < Sn)
            pf[tid * PAD + fb] = ws[0][tid] + ws[1][tid] + ws[2][tid] + ws[3][tid];
    }
}

__global__ __launch_bounds__(1024) void finish_kernel(const float* __restrict__ pf,
                                                      const float* __restrict__ po,
                                                      float* __restrict__ out) {
    __shared__ float acc[2 * Sn];
    const int tid  = threadIdx.x;
    const int lane = tid & 63;
    if (tid < NC) qctr[tid] = 0;            // reset tile queue for next graph replay
    if (tid < 2 * Sn) acc[tid] = 0.0f;
    __syncthreads();

    // ---- fret partials: 768 entries, one coalesced load per thread ----
    float fs[Sn], os[Sn];
    #pragma unroll
    for (int s = 0; s < Sn; ++s) {
        fs[s] = (tid < NFB) ? pf[s * PAD + tid] : 0.0f;
        float u = 0.0f;
        for (int i = lane; i < OBLK; i += 64) u += 0.0f;   // placeholder keeps shape
        os[s] = 0.0f;
    }
    // ---- onset partials: wave w sums string w (188 entries) ----
    const int wv = tid >> 6;
    if (wv < Sn) {
        float v = 0.0f;
        for (int i = lane; i < OBLK; i += 64) v += po[wv * PAD + i];
        os[wv] = v;                          // only os[own string] used below
    }
    #pragma unroll
    for (int off = 32; off; off >>= 1) {
        #pragma unroll
        for (int s = 0; s < Sn; ++s) fs[s] += __shfl_xor(fs[s], off, 64);
    }
    if (wv < Sn) {
        float v = os[wv];
        #pragma unroll
        for (int off = 32; off; off >>= 1) v += __shfl_xor(v, off, 64);
        if (lane == 0) acc[Sn + wv] = v;
    }
    if (lane == 0) {
        #pragma unroll
        for (int s = 0; s < Sn; ++s) atomicAdd(&acc[s], fs[s]);
    }
    __syncthreads();

    if (tid == 0) {
        float fret = 0.0f, on = 0.0f, fsv[Sn], osv[Sn];
        #pragma unroll
        for (int s = 0; s < Sn; ++s) {
            fsv[s] = acc[s] * (1.0f / Bn);  // mean over batch
            osv[s] = acc[Sn + s];
            fret += fsv[s];
            on   += osv[s];
        }
        out[0] = 0.5f * fret + 0.5f * on;   // WEIGHT_FRET_ONSET = 0.5
        out[1] = fret;
        out[2] = on;
        #pragma unroll
        for (int s = 0; s < Sn; ++s) { out[3 + s] = fsv[s]; out[9 + s] = osv[s]; }
    }
}

extern "C" void kernel_launch(void* const* d_in, const int* in_sizes, int n_in,
                              void* d_out, int out_size, void* d_ws, size_t ws_size,
                              hipStream_t stream) {
    const float* output_fret  = (const float*)d_in[0];
    const int*   target_fret  = (const int*)d_in[1];
    const float* output_onset = (const float*)d_in[2];
    const float* target_onset = (const float*)d_in[3];
    float* pf  = (float*)d_ws;                 // [Sn][PAD]
    float* po  = pf + Sn * PAD;                // [Sn][PAD]
    float* out = (float*)d_out;

    main_kernel<<<GRID, BDIM, 0, stream>>>((const float4*)output_fret, target_fret,
                                           output_onset, target_onset, pf, po);
    finish_kernel<<<1, 1024, 0, stream>>>(pf, po, out);
}

// Round 12
// 24.910 us; speedup vs baseline: 2.7166x; 2.7166x over previous
//
#include <hip/hip_runtime.h>
#include <math.h>

constexpr int Bn = 64, Sn = 6, Tn = 2000, Cn = 25;
constexpr int COLS = Sn * Tn;              // 12000
constexpr int ROWS = Bn * Sn * Tn;         // 768000
constexpr int BDIM = 256;
constexpr int WV   = 4;                    // waves per block

// ---- fret: each wave pipelines NT=4 tiles of 64 rows, double-buffered (R7) ----
constexpr int TROWS = 64;                  // rows per tile (1 per lane)
constexpr int TF4   = TROWS * Cn / 4;      // 400 float4 per tile
constexpr int NT    = 4;                   // tiles per wave
constexpr int RPW   = NT * TROWS;          // 256 rows per wave
constexpr int RPB   = WV * RPW;            // 1024 rows per block
constexpr int FBLK  = ROWS / RPB;          // 750 fret blocks (exact)
constexpr int FPAD  = 768;

// ---- onset: 64 cols per block, wave w covers batch [16w,16w+16) (R7 verbatim) ----
constexpr int OCOLS = 64;
constexpr int OBLK  = (COLS + OCOLS - 1) / OCOLS;   // 188 onset blocks
constexpr int OPAD  = 192;
constexpr int GRID  = FBLK + OBLK;         // 938; fret FIRST (LPT: short onset fills tail)

typedef const __attribute__((address_space(1))) unsigned int guint;
typedef __attribute__((address_space(3)))       unsigned int luint;

// Segmented (<=2 contiguous strings per wave) butterfly reduce + LDS add.
static __device__ __forceinline__ void seg_reduce_add(float* ls, int s, float v, int lane) {
    const int s0 = __shfl(s, 0, 64);
    const int s1 = __shfl(s, 63, 64);
    if (s0 == s1) {                         // wave-uniform branch
        float a = v;
        #pragma unroll
        for (int off = 32; off; off >>= 1) a += __shfl_xor(a, off, 64);
        if (lane == 0) atomicAdd(&ls[s0], a);
    } else {
        float a = (s == s0) ? v : 0.0f;
        float b = (s == s0) ? 0.0f : v;
        #pragma unroll
        for (int off = 32; off; off >>= 1) {
            a += __shfl_xor(a, off, 64);
            b += __shfl_xor(b, off, 64);
        }
        if (lane == 0) { atomicAdd(&ls[s0], a); atomicAdd(&ls[s1], b); }
    }
}

__global__ __launch_bounds__(BDIM) void main_kernel(const float4* __restrict__ x4,
                                                    const int*    __restrict__ tgt,
                                                    const float*  __restrict__ ox,
                                                    const float*  __restrict__ ot,
                                                    float* __restrict__ pf,
                                                    float* __restrict__ po) {
    __shared__ float4 buf4[WV][2][TF4];    // 51.2 KB: wave-private double buffers
    __shared__ float  ws[WV][Sn];          // per-wave string partials
    const int tid  = threadIdx.x;
    const int lane = tid & 63;
    const int w    = tid >> 6;
    if (lane < Sn) ws[w][lane] = 0.0f;     // same-wave LDS ordering: no barrier

    if (blockIdx.x >= FBLK) {
        // ============ onset path: softmax over B, batch-split across waves ============
        const int cb  = blockIdx.x - FBLK;            // onset blocks dispatched LAST
        const int col = cb * OCOLS + lane;            // wave-local column
        float4* ob4 = &buf4[0][0][0];                 // reuse fret buffer: [4][64] float4
        float M = -INFINITY, S = 0.0f, ts = 0.0f, txs = 0.0f;
        if (col < COLS) {
            const int b0 = w * 16;
            #pragma unroll
            for (int h = 0; h < 2; ++h) {             // two 8-batch chunks (reg pressure)
                float xv[8], tv[8];
                #pragma unroll
                for (int k = 0; k < 8; ++k) xv[k] = ox[(b0 + h * 8 + k) * COLS + col];
                #pragma unroll
                for (int k = 0; k < 8; ++k) tv[k] = ot[(b0 + h * 8 + k) * COLS + col];
                float cm = -INFINITY;
                #pragma unroll
                for (int k = 0; k < 8; ++k) cm = fmaxf(cm, xv[k]);
                float cs = 0.0f;
                #pragma unroll
                for (int k = 0; k < 8; ++k) cs += __expf(xv[k] - cm);
                const float nm = fmaxf(M, cm);
                S = S * __expf(M - nm) + cs * __expf(cm - nm);   // exp(-inf)=0 first iter
                M = nm;
                #pragma unroll
                for (int k = 0; k < 8; ++k) { ts += tv[k]; txs += tv[k] * xv[k]; }
            }
        }
        ob4[w * OCOLS + lane] = make_float4(M, S, ts, txs);   // per-wave partial
        __syncthreads();
        if (tid < OCOLS) {                            // wave 0 merges the 4 partials
            float on = 0.0f;
            int   s  = Sn - 1;
            const int c = cb * OCOLS + tid;
            if (c < COLS) {
                s = c / Tn;
                float4 p0 = ob4[0 * OCOLS + tid];
                float Mm = p0.x, Sm = p0.y, tsm = p0.z, txm = p0.w;
                #pragma unroll
                for (int q = 1; q < WV; ++q) {
                    const float4 p = ob4[q * OCOLS + tid];
                    const float nm = fmaxf(Mm, p.x);
                    Sm  = Sm * __expf(Mm - nm) + p.y * __expf(p.x - nm);
                    Mm  = nm;
                    tsm += p.z; txm += p.w;
                }
                on = tsm * (Mm + __logf(Sm)) - txm;
            }
            seg_reduce_add(ws[0], s, on, tid);        // wave 0 only, same-wave DS order
            if (tid < Sn) po[tid * OPAD + cb] = ws[0][tid];
        }
    } else {
        // ===== fret path: wave-autonomous double-buffered async pipeline (R7) =====
        const int fb    = blockIdx.x;                 // fret blocks dispatched FIRST
        const int wrow0 = fb * RPB + w * RPW;         // wave's first row (mult of 4)
        const float4* gw = x4 + (long)(wrow0 / 4) * Cn;   // = wrow0*25/4
        float4* bb = &buf4[w][0][0];                  // [2][TF4] wave-private

        // All 4 targets upfront: 4 coalesced 256B dword loads (4 VGPR, static).
        int tcs[NT];
        #pragma unroll
        for (int t = 0; t < NT; ++t) tcs[t] = tgt[wrow0 + t * TROWS + lane];

        // stage(t): 7 x global_load_lds (6 full + 1 exec-masked), 1KB each.
        // LDS dest = wave-uniform base (+lane*16 by HW); global src per-lane.
        auto stage = [&](int t) {
            const int p = t & 1;
            const float4* gs = gw + (long)t * TF4 + lane;
            #pragma unroll
            for (int k = 0; k < 6; ++k)
                __builtin_amdgcn_global_load_lds((guint*)(gs + k * 64),
                                                 (luint*)(bb + p * TF4 + k * 64), 16, 0, 0);
            if (lane < 16)
                __builtin_amdgcn_global_load_lds((guint*)(gs + 384),
                                                 (luint*)(bb + p * TF4 + 384), 16, 0, 0);
        };

        auto compute = [&](int t) {
            const int tc = tcs[t];
            const float* rp = (const float*)(bb + (t & 1) * TF4) + lane * Cn;  // stride 25
            const float xt = rp[tc];                  // 1 ds_read replaces 50 VALU ops
            float m = -INFINITY;
            #pragma unroll
            for (int c = 0; c < Cn; ++c) m = fmaxf(m, rp[c]);
            float ss = 0.0f;
            #pragma unroll
            for (int c = 0; c < Cn; ++c) ss += __expf(rp[c] - m);
            const float nll = m + __logf(ss) - xt;
            const int s = ((wrow0 + t * TROWS + lane) / Tn) % Sn;  // tile: <=2 strings
            seg_reduce_add(ws[w], s, nll, lane);
        };

        stage(0);
        stage(1);                                     // 14 tile-loads + 4 tgt in flight
        #pragma unroll
        for (int t = 0; t < NT; ++t) {
            if (t < NT - 1)
                asm volatile("s_waitcnt vmcnt(7)" ::: "memory");   // tile t done; next flying
            else
                asm volatile("s_waitcnt vmcnt(0)" ::: "memory");   // final tile drain
            compute(t);
            if (t + 2 < NT) {
                asm volatile("s_waitcnt lgkmcnt(0)" ::: "memory"); // buf[t&1] reads retired
                stage(t + 2);                                      // overwrite buffer t&1
            }
        }
        __syncthreads();                              // once per block: combine 4 waves
        if (tid < Sn)
            pf[tid * FPAD + fb] = ws[0][tid] + ws[1][tid] + ws[2][tid] + ws[3][tid];
    }
}

__global__ __launch_bounds__(1024) void finish_kernel(const float* __restrict__ pf,
                                                      const float* __restrict__ po,
                                                      float* __restrict__ out) {
    __shared__ float acc[2 * Sn];
    const int tid  = threadIdx.x;
    const int lane = tid & 63;
    if (tid < 2 * Sn) acc[tid] = 0.0f;
    __syncthreads();

    // ---- fret partials: 6 coalesced sweeps over 750 entries ----
    float fs[Sn];
    #pragma unroll
    for (int s = 0; s < Sn; ++s) {
        float v = 0.0f;
        for (int i = tid; i < FBLK; i += 1024) v += pf[s * FPAD + i];
        fs[s] = v;
    }
    #pragma unroll
    for (int off = 32; off; off >>= 1) {
        #pragma unroll
        for (int s = 0; s < Sn; ++s) fs[s] += __shfl_xor(fs[s], off, 64);
    }
    if (lane == 0) {
        #pragma unroll
        for (int s = 0; s < Sn; ++s) atomicAdd(&acc[s], fs[s]);
    }

    // ---- onset partials: wave w sums string w (188 entries) ----
    const int wv = tid >> 6;
    if (wv < Sn) {
        float v = 0.0f;
        for (int i = lane; i < OBLK; i += 64) v += po[wv * OPAD + i];
        #pragma unroll
        for (int off = 32; off; off >>= 1) v += __shfl_xor(v, off, 64);
        if (lane == 0) acc[Sn + wv] = v;
    }
    __syncthreads();

    if (tid == 0) {
        float fret = 0.0f, on = 0.0f, fsv[Sn], osv[Sn];
        #pragma unroll
        for (int s = 0; s < Sn; ++s) {
            fsv[s] = acc[s] * (1.0f / Bn);            // mean over batch
            osv[s] = acc[Sn + s];
            fret += fsv[s];
            on   += osv[s];
        }
        out[0] = 0.5f * fret + 0.5f * on;             // WEIGHT_FRET_ONSET = 0.5
        out[1] = fret;
        out[2] = on;
        #pragma unroll
        for (int s = 0; s < Sn; ++s) { out[3 + s] = fsv[s]; out[9 + s] = osv[s]; }
    }
}

extern "C" void kernel_launch(void* const* d_in, const int* in_sizes, int n_in,
                              void* d_out, int out_size, void* d_ws, size_t ws_size,
                              hipStream_t stream) {
    const float* output_fret  = (const float*)d_in[0];
    const int*   target_fret  = (const int*)d_in[1];
    const float* output_onset = (const float*)d_in[2];
    const float* target_onset = (const float*)d_in[3];
    float* pf  = (float*)d_ws;                 // [Sn][FPAD]
    float* po  = pf + Sn * FPAD;               // [Sn][OPAD]
    float* out = (float*)d_out;

    main_kernel<<<GRID, BDIM, 0, stream>>>((const float4*)output_fret, target_fret,
                                           output_onset, target_onset, pf, po);
    finish_kernel<<<1, 1024, 0, stream>>>(pf, po, out);
}